// Round 1
// baseline (1192.561 us; speedup 1.0000x reference)
//
#include <hip/hip_runtime.h>
#include <math.h>

#define NCLS 19
#define NPROTO 10
#define KM 190
#define KMP 192
#define D 720
#define TP 64
#define KC 48
#define NCH 15

__device__ __forceinline__ float wred_sum(float v) {
#pragma unroll
  for (int o = 32; o > 0; o >>= 1) v += __shfl_xor(v, o, 64);
  return v;
}
__device__ __forceinline__ float wred_max(float v) {
#pragma unroll
  for (int o = 32; o > 0; o >>= 1) v = fmaxf(v, __shfl_xor(v, o, 64));
  return v;
}
__device__ __forceinline__ double wred_sumd(double v) {
#pragma unroll
  for (int o = 32; o > 0; o >>= 1) v += __shfl_xor(v, o, 64);
  return v;
}

// ---------------- prep: G2[d]=g^2, GB[d]=g*b, C3={Sum g^2, Sum g b, Sum b^2}
__global__ void prep_gb(const float* __restrict__ fg, const float* __restrict__ fb,
                        float* __restrict__ G2, float* __restrict__ GB,
                        float* __restrict__ C3) {
  const int t = threadIdx.x;
  float cg = 0.f, cgb = 0.f, cb = 0.f;
  for (int d2 = t; d2 < D; d2 += 256) {
    const float g = fg[d2], b = fb[d2];
    G2[d2] = g * g;
    GB[d2] = g * b;
    cg = fmaf(g, g, cg);
    cgb = fmaf(g, b, cgb);
    cb = fmaf(b, b, cb);
  }
  __shared__ float red[3][4];
  cg = wred_sum(cg); cgb = wred_sum(cgb); cb = wred_sum(cb);
  const int w = t >> 6, lane = t & 63;
  if (lane == 0) { red[0][w] = cg; red[1][w] = cgb; red[2][w] = cb; }
  __syncthreads();
  if (t == 0) {
    C3[0] = red[0][0] + red[0][1] + red[0][2] + red[0][3];
    C3[1] = red[1][0] + red[1][1] + red[1][2] + red[1][3];
    C3[2] = red[2][0] + red[2][1] + red[2][2] + red[2][3];
  }
}

// ---------------- proto prep: pgT[d][j] = g_d * Phat[j][d]; A[j]=Sum g*Phat; B[j]=Sum b*Phat
__global__ void proto_prep(const float* __restrict__ pr, const float* __restrict__ fg,
                           const float* __restrict__ fb, float* __restrict__ pgT,
                           float* __restrict__ Av, float* __restrict__ Bv) {
  const int j = blockIdx.x, lane = threadIdx.x;
  if (j >= KM) {  // zero pad columns 190,191
#pragma unroll
    for (int jj = 0; jj < 12; ++jj) {
      const int d2 = lane + 64 * jj;
      if (d2 < D) pgT[(size_t)d2 * KMP + j] = 0.f;
    }
    if (lane == 0) { Av[j] = 0.f; Bv[j] = 0.f; }
    return;
  }
  float pv[12];
  float sp = 0.f;
#pragma unroll
  for (int jj = 0; jj < 12; ++jj) {
    const int d2 = lane + 64 * jj;
    pv[jj] = (d2 < D) ? pr[(size_t)j * D + d2] : 0.f;
    sp = fmaf(pv[jj], pv[jj], sp);
  }
  sp = wred_sum(sp);
  const float ip = 1.f / fmaxf(sqrtf(sp), 1e-12f);
  float sa = 0.f, sb = 0.f;
#pragma unroll
  for (int jj = 0; jj < 12; ++jj) {
    const int d2 = lane + 64 * jj;
    if (d2 < D) {
      const float ph = pv[jj] * ip;
      const float g = fg[d2], b = fb[d2];
      pgT[(size_t)d2 * KMP + j] = g * ph;
      sa = fmaf(g, ph, sa);
      sb = fmaf(b, ph, sb);
    }
  }
  sa = wred_sum(sa); sb = wred_sum(sb);
  if (lane == 0) { Av[j] = sa; Bv[j] = sb; }
}

// ---------------- main pass: GEMM on raw x + per-pixel affine fixup + epilogue
__global__ __launch_bounds__(256, 3) void gemm_main(
    const float* __restrict__ x, const float* __restrict__ pgT,
    const float* __restrict__ Av, const float* __restrict__ Bv,
    const float* __restrict__ G2, const float* __restrict__ GB,
    const float* __restrict__ C3, const int* __restrict__ gt,
    float* __restrict__ out_seg, float* __restrict__ contrast,
    float* __restrict__ se, int* __restrict__ flags,
    const float* __restrict__ mn_g, const float* __restrict__ mn_b,
    const float* __restrict__ pn_g, const float* __restrict__ pn_b, int N) {
  __shared__ union {
    struct {
      float XT[KC][TP];    // [k][pixel]
      float PT[KC][KMP];   // [k][proto]
      float G2c[KC], GBc[KC];
    } st;
    float SIM[TP][KMP];
    float stats[5][4][TP];
  } S;
  __shared__ float A_s[KMP], B_s[KMP];
  __shared__ float PGn[KMP], PBn[KMP];
  __shared__ float MGn[32], MBn[32];
  __shared__ float MU[TP], RS[TP], IL[TP];

  const int t = threadIdx.x;
  const int n0 = blockIdx.x * TP;
  const int pg = t & 15;   // pixels 4pg..4pg+3
  const int g = t >> 4;    // protos 12g..12g+11
  const int sp = t & 63, sl = t >> 6;

  if (t < KMP) { A_s[t] = Av[t]; B_s[t] = Bv[t]; }
  if (t < KM) { PGn[t] = pn_g[t]; PBn[t] = pn_b[t]; }
  if (t < NCLS) { MGn[t] = mn_g[t]; MBn[t] = mn_b[t]; }

  float acc[4][12];
#pragma unroll
  for (int i = 0; i < 4; ++i)
#pragma unroll
    for (int jj = 0; jj < 12; ++jj) acc[i][jj] = 0.f;

  float s0 = 0.f, q = 0.f, s1 = 0.f, s2 = 0.f, s3 = 0.f;

  for (int c = 0; c < NCH; ++c) {
    const int k0 = c * KC;
    __syncthreads();
    // stage X tile transposed: 768 float4
#pragma unroll
    for (int j = 0; j < 3; ++j) {
      const int i = t + 256 * j;
      const int pix = i / 12, kq = i % 12;
      const float4 v = *(const float4*)&x[(size_t)(n0 + pix) * D + k0 + 4 * kq];
      S.st.XT[4 * kq + 0][pix] = v.x;
      S.st.XT[4 * kq + 1][pix] = v.y;
      S.st.XT[4 * kq + 2][pix] = v.z;
      S.st.XT[4 * kq + 3][pix] = v.w;
    }
    // stage P tile: rows contiguous
#pragma unroll
    for (int j = 0; j < 9; ++j) {
      const int i = t + 256 * j;
      const int kk = i / 48, c4 = i % 48;
      *(float4*)&S.st.PT[kk][4 * c4] =
          *(const float4*)&pgT[(size_t)(k0 + kk) * KMP + 4 * c4];
    }
    if (t < KC) { S.st.G2c[t] = G2[k0 + t]; S.st.GBc[t] = GB[k0 + t]; }
    __syncthreads();
    // per-pixel stats (wave sl covers k-slice 12*sl..12*sl+11)
#pragma unroll
    for (int kk2 = 0; kk2 < 12; ++kk2) {
      const int kk = 12 * sl + kk2;
      const float xv = S.st.XT[kk][sp];
      const float g2 = S.st.G2c[kk], gb = S.st.GBc[kk];
      s0 += xv;
      q = fmaf(xv, xv, q);
      s1 = fmaf(xv, g2, s1);
      s2 = fmaf(xv * xv, g2, s2);
      s3 = fmaf(xv, gb, s3);
    }
    // register-tile FMA
#pragma unroll 4
    for (int kk = 0; kk < KC; ++kk) {
      const float4 xv = *(const float4*)&S.st.XT[kk][4 * pg];
      const float4 pa = *(const float4*)&S.st.PT[kk][12 * g];
      const float4 pb = *(const float4*)&S.st.PT[kk][12 * g + 4];
      const float4 pc = *(const float4*)&S.st.PT[kk][12 * g + 8];
      const float xs[4] = {xv.x, xv.y, xv.z, xv.w};
      const float ps[12] = {pa.x, pa.y, pa.z, pa.w, pb.x, pb.y,
                            pb.z, pb.w, pc.x, pc.y, pc.z, pc.w};
#pragma unroll
      for (int i = 0; i < 4; ++i)
#pragma unroll
        for (int jj = 0; jj < 12; ++jj)
          acc[i][jj] = fmaf(xs[i], ps[jj], acc[i][jj]);
    }
  }

  __syncthreads();
  S.stats[0][sl][sp] = s0;
  S.stats[1][sl][sp] = q;
  S.stats[2][sl][sp] = s1;
  S.stats[3][sl][sp] = s2;
  S.stats[4][sl][sp] = s3;
  __syncthreads();
  if (t < TP) {
    float S0 = 0.f, Q = 0.f, S1 = 0.f, S2 = 0.f, S3 = 0.f;
#pragma unroll
    for (int s = 0; s < 4; ++s) {
      S0 += S.stats[0][s][t];
      Q += S.stats[1][s][t];
      S1 += S.stats[2][s][t];
      S2 += S.stats[3][s][t];
      S3 += S.stats[4][s][t];
    }
    const float Cgg = C3[0], Cgb = C3[1], Cbb = C3[2];
    const float mu = S0 / 720.f;
    const float var = Q / 720.f - mu * mu;
    const float rs = 1.f / sqrtf(var + 1e-5f);
    const float L2v = rs * rs * (S2 - 2.f * mu * S1 + mu * mu * Cgg) +
                      2.f * rs * (S3 - mu * Cgb) + Cbb;
    MU[t] = mu;
    RS[t] = rs;
    IL[t] = 1.f / fmaxf(sqrtf(fmaxf(L2v, 0.f)), 1e-12f);
  }
  __syncthreads();
  // fixup to true cosine sims, write SIM
#pragma unroll
  for (int i = 0; i < 4; ++i) {
    const int pix = 4 * pg + i;
    const float mu = MU[pix], rs = RS[pix], il = IL[pix];
#pragma unroll
    for (int jj = 0; jj < 12; ++jj) {
      const int j = 12 * g + jj;
      acc[i][jj] = (rs * (acc[i][jj] - mu * A_s[j]) + B_s[j]) * il;
    }
    *(float4*)&S.SIM[pix][12 * g] =
        make_float4(acc[i][0], acc[i][1], acc[i][2], acc[i][3]);
    *(float4*)&S.SIM[pix][12 * g + 4] =
        make_float4(acc[i][4], acc[i][5], acc[i][6], acc[i][7]);
    *(float4*)&S.SIM[pix][12 * g + 8] =
        make_float4(acc[i][8], acc[i][9], acc[i][10], acc[i][11]);
  }
  __syncthreads();

  // epilogue: wave w handles pixels 16w..16w+15
  const int w = t >> 6, lane = t & 63;
  const int j0 = lane, j1 = lane + 64, j2 = lane + 128;
  const bool ok2 = (j2 < KM);
  for (int pi = 0; pi < 16; ++pi) {
    const int pix = w * 16 + pi;
    const int n = n0 + pix;
    const float sv0 = S.SIM[pix][j0];
    const float sv1 = S.SIM[pix][j1];
    const float sv2 = ok2 ? S.SIM[pix][j2] : 0.f;
    // LN over 190 -> contrast_logits
    float sum = sv0 + sv1 + sv2;
    sum = wred_sum(sum);
    const float mu = sum / 190.f;
    const float d0 = sv0 - mu, d1 = sv1 - mu, d2v = ok2 ? (sv2 - mu) : 0.f;
    float vs = d0 * d0 + d1 * d1 + d2v * d2v;
    vs = wred_sum(vs);
    const float rstd = 1.f / sqrtf(vs / 190.f + 1e-5f);
    contrast[(size_t)n * KM + j0] = d0 * rstd * PGn[j0] + PBn[j0];
    contrast[(size_t)n * KM + j1] = d1 * rstd * PGn[j1] + PBn[j1];
    if (ok2) contrast[(size_t)n * KM + j2] = d2v * rstd * PGn[j2] + PBn[j2];
    // stash this pixel's own-class sims
    const int g0 = gt[n];
    const int b10 = g0 * 10;
    if (j0 >= b10 && j0 < b10 + 10) se[(size_t)n * 10 + (j0 - b10)] = sv0;
    if (j1 >= b10 && j1 < b10 + 10) se[(size_t)n * 10 + (j1 - b10)] = sv1;
    if (ok2 && j2 >= b10 && j2 < b10 + 10) se[(size_t)n * 10 + (j2 - b10)] = sv2;
    // per-class max + LN over 19 -> out_seg, pred
    float mx = -3.0e38f;
    if (lane < NCLS) {
      const float* row = &S.SIM[pix][lane * 10];
#pragma unroll
      for (int m2 = 0; m2 < 10; ++m2) mx = fmaxf(mx, row[m2]);
    }
    float s19 = wred_sum(lane < NCLS ? mx : 0.f);
    const float mu19 = s19 / 19.f;
    const float dv = (lane < NCLS) ? (mx - mu19) : 0.f;
    float v19 = wred_sum(dv * dv);
    const float rs19 = 1.f / sqrtf(v19 / 19.f + 1e-5f);
    float key = -3.0e38f;
    if (lane < NCLS) {
      const float os = dv * rs19 * MGn[lane] + MBn[lane];
      out_seg[(size_t)n * NCLS + lane] = os;
      key = os;
    }
    const float kmax = wred_max(key);
    const unsigned long long bm = __ballot(key == kmax);
    const int pred = __ffsll((unsigned long long)bm) - 1;
    if (lane == 0) flags[n] = (pred == g0) ? 1 : 0;
  }
}

// ---------------- Sinkhorn column-sum pass (one iteration's numerator)
__global__ void sk_colsum(const float* __restrict__ se, const int* __restrict__ gt,
                          const float* __restrict__ u, float* __restrict__ partials,
                          int iter, int nblk, int N) {
  __shared__ float Sl[KMP];
  const int t = threadIdx.x;
  if (t < KMP) Sl[t] = 0.f;
  __syncthreads();
  const int n = blockIdx.x * 256 + t;
  if (n < N) {
    const int b10 = gt[n] * 10;
    float e[10];
#pragma unroll
    for (int m = 0; m < 10; ++m) e[m] = expf(se[(size_t)n * 10 + m] / 0.05f);
    float a = 1.f;
    if (iter > 0) {
      float s = 0.f;
#pragma unroll
      for (int m = 0; m < 10; ++m) s += e[m] * u[b10 + m];
      a = (s > 0.f) ? 1.f / s : 0.f;
    }
#pragma unroll
    for (int m = 0; m < 10; ++m) atomicAdd(&Sl[b10 + m], a * e[m]);
  }
  __syncthreads();
  if (t < KM) partials[(size_t)t * nblk + blockIdx.x] = Sl[t];
}

__global__ void sk_reduce(const float* __restrict__ partials, float* __restrict__ u,
                          int nblk) {
  const int j = blockIdx.x, lane = threadIdx.x;
  double s = 0.0;
  for (int b = lane; b < nblk; b += 64) s += (double)partials[(size_t)j * nblk + b];
  s = wred_sumd(s);
  if (lane == 0) u[j] = (s > 0.0) ? (float)(1.0 / (10.0 * s)) : 0.f;
}

__global__ void sk_final(const float* __restrict__ se, const int* __restrict__ gt,
                         const float* __restrict__ u, const int* __restrict__ flags,
                         float* __restrict__ ptgt, int* __restrict__ list,
                         int* __restrict__ cnt, int* __restrict__ n_km, int N) {
  const int n = blockIdx.x * 256 + threadIdx.x;
  if (n >= N) return;
  const int g0 = gt[n], b10 = g0 * 10;
  float best = -1.f;
  int bi = 0;
#pragma unroll
  for (int m = 0; m < 10; ++m) {
    const float v = expf(se[(size_t)n * 10 + m] / 0.05f) * u[b10 + m];
    if (v > best) { best = v; bi = m; }
  }
  ptgt[n] = (float)(bi + 10 * g0);
  if (flags[n]) {
    atomicAdd(&n_km[b10 + bi], 1);
    const int p = atomicAdd(cnt, 1);
    list[p] = n | (bi << 20) | (g0 << 24);
  }
}

// ---------------- f accumulation over correct pixels (wave per pixel)
__global__ void f_accum(const float* __restrict__ x, const float* __restrict__ fg,
                        const float* __restrict__ fb, const int* __restrict__ list,
                        const int* __restrict__ cnt, float* __restrict__ f) {
  const int lane = threadIdx.x & 63;
  const int wid = (blockIdx.x * blockDim.x + threadIdx.x) >> 6;
  const int nw = (gridDim.x * blockDim.x) >> 6;
  const int total = *cnt;
  for (int i = wid; i < total; i += nw) {
    const int packed = list[i];
    const int n = packed & 0xFFFFF;
    const int m = (packed >> 20) & 0xF;
    const int k = (packed >> 24) & 0x1F;
    float xv[12];
    float s0 = 0.f, q = 0.f;
#pragma unroll
    for (int jj = 0; jj < 12; ++jj) {
      const int d2 = lane + 64 * jj;
      xv[jj] = (d2 < D) ? x[(size_t)n * D + d2] : 0.f;
      s0 += xv[jj];
      q = fmaf(xv[jj], xv[jj], q);
    }
    s0 = wred_sum(s0);
    q = wred_sum(q);
    const float mu = s0 / 720.f;
    const float var = q / 720.f - mu * mu;
    const float rs = 1.f / sqrtf(var + 1e-5f);
    float cv[12];
    float l2 = 0.f;
#pragma unroll
    for (int jj = 0; jj < 12; ++jj) {
      const int d2 = lane + 64 * jj;
      if (d2 < D) {
        cv[jj] = (xv[jj] - mu) * rs * fg[d2] + fb[d2];
        l2 = fmaf(cv[jj], cv[jj], l2);
      } else {
        cv[jj] = 0.f;
      }
    }
    l2 = wred_sum(l2);
    const float il = 1.f / fmaxf(sqrtf(l2), 1e-12f);
    float* frow = &f[(size_t)(k * 10 + m) * D];
#pragma unroll
    for (int jj = 0; jj < 12; ++jj) {
      const int d2 = lane + 64 * jj;
      if (d2 < D) atomicAdd(&frow[d2], cv[jj] * il);
    }
  }
}

// ---------------- prototype update (one wave per proto row)
__global__ void protos_out(const float* __restrict__ pr, const float* __restrict__ f,
                           const int* __restrict__ n_km, float* __restrict__ out) {
  const int j = blockIdx.x, lane = threadIdx.x;
  float pv[12], fv[12];
  float sp = 0.f, sf = 0.f;
#pragma unroll
  for (int jj = 0; jj < 12; ++jj) {
    const int d2 = lane + 64 * jj;
    pv[jj] = (d2 < D) ? pr[(size_t)j * D + d2] : 0.f;
    fv[jj] = (d2 < D) ? f[(size_t)j * D + d2] : 0.f;
    sp = fmaf(pv[jj], pv[jj], sp);
    sf = fmaf(fv[jj], fv[jj], sf);
  }
  sp = wred_sum(sp);
  sf = wred_sum(sf);
  const float ip = 1.f / fmaxf(sqrtf(sp), 1e-12f);
  const float iff = 1.f / fmaxf(sqrtf(sf), 1e-12f);
  const bool valid = n_km[j] > 0;
  float vv[12];
  float sv = 0.f;
#pragma unroll
  for (int jj = 0; jj < 12; ++jj) {
    const float ph = pv[jj] * ip;
    vv[jj] = valid ? (0.999f * ph + 0.001f * (fv[jj] * iff)) : ph;
    sv = fmaf(vv[jj], vv[jj], sv);
  }
  sv = wred_sum(sv);
  const float ivv = 1.f / fmaxf(sqrtf(sv), 1e-12f);
#pragma unroll
  for (int jj = 0; jj < 12; ++jj) {
    const int d2 = lane + 64 * jj;
    if (d2 < D) out[(size_t)j * D + d2] = vv[jj] * ivv;
  }
}

extern "C" void kernel_launch(void* const* d_in, const int* in_sizes, int n_in,
                              void* d_out, int out_size, void* d_ws, size_t ws_size,
                              hipStream_t stream) {
  const float* x = (const float*)d_in[0];
  const float* protos = (const float*)d_in[1];
  const float* fn_g = (const float*)d_in[2];
  const float* fn_b = (const float*)d_in[3];
  const float* mn_g = (const float*)d_in[4];
  const float* mn_b = (const float*)d_in[5];
  const float* pn_g = (const float*)d_in[6];
  const float* pn_b = (const float*)d_in[7];
  const int* gt = (const int*)d_in[8];
  const int N = in_sizes[0] / D;

  float* out_seg = (float*)d_out;
  float* contrast = out_seg + (size_t)N * NCLS;
  float* ptgt = contrast + (size_t)N * KM;
  float* pnew = ptgt + (size_t)N;

  char* ws = (char*)d_ws;
  size_t off = 0;
  auto alloc = [&](size_t bytes) {
    char* p = ws + off;
    off = (off + bytes + 255) & ~(size_t)255;
    return p;
  };
  const int nblk = (N + 255) / 256;
  float* pgT = (float*)alloc((size_t)D * KMP * 4);
  float* Av = (float*)alloc(KMP * 4);
  float* Bv = (float*)alloc(KMP * 4);
  float* G2 = (float*)alloc(D * 4);
  float* GB = (float*)alloc(D * 4);
  float* C3 = (float*)alloc(4 * 4);
  float* se = (float*)alloc((size_t)N * 10 * 4);
  float* partials = (float*)alloc((size_t)KM * nblk * 4);
  float* u = (float*)alloc(KMP * 4);
  float* f = (float*)alloc((size_t)KM * D * 4);
  int* n_km = (int*)alloc(KMP * 4);
  int* flags = (int*)alloc((size_t)N * 4);
  int* list = (int*)alloc((size_t)N * 4);
  int* cnt = (int*)alloc(256);

  hipMemsetAsync(f, 0, (size_t)KM * D * 4, stream);
  hipMemsetAsync(n_km, 0, KMP * 4, stream);
  hipMemsetAsync(cnt, 0, 4, stream);

  prep_gb<<<1, 256, 0, stream>>>(fn_g, fn_b, G2, GB, C3);
  proto_prep<<<KMP, 64, 0, stream>>>(protos, fn_g, fn_b, pgT, Av, Bv);
  gemm_main<<<N / TP, 256, 0, stream>>>(x, pgT, Av, Bv, G2, GB, C3, gt, out_seg,
                                        contrast, se, flags, mn_g, mn_b, pn_g,
                                        pn_b, N);
  for (int it = 0; it < 3; ++it) {
    sk_colsum<<<nblk, 256, 0, stream>>>(se, gt, u, partials, it, nblk, N);
    sk_reduce<<<KM, 64, 0, stream>>>(partials, u, nblk);
  }
  sk_final<<<nblk, 256, 0, stream>>>(se, gt, u, flags, ptgt, list, cnt, n_km, N);
  f_accum<<<256, 256, 0, stream>>>(x, fn_g, fn_b, list, cnt, f);
  protos_out<<<KM, 64, 0, stream>>>(protos, f, n_km, pnew);
}